// Round 1
// baseline (281.988 us; speedup 1.0000x reference)
//
#include <hip/hip_runtime.h>

// SplineGCN on a fixed batched 8-neighborhood grid graph.
// Exploits structure: pseudo-coords depend only on edge direction (dr,dc), so
// the degree-1 B-spline weighting collapses to 8 fixed per-direction effective
// weight matrices:  dir (dr,dc):  row-dim dr=-1 -> {k=0, w=1}, dr=0 -> {1:.5, 2:.5},
// dr=1 -> {3, w=1}; same for columns; Weff[d] = sum wr*wc * W[kr*4+kc].
// Each layer: out[p] = elu( (sum_d x[p - d] @ Weff[d]) / deg(p) + x[p] @ root + b )

__global__ __launch_bounds__(256) void prep_weff_kernel(
    const float* __restrict__ W, float* __restrict__ weff, int cinout) {
  int idx = blockIdx.x * 256 + threadIdx.x;
  if (idx >= 8 * cinout) return;
  int d = idx / cinout;
  int rem = idx - d * cinout;
  int dd = d >= 4 ? d + 1 : d;          // skip (0,0)
  int dr = dd / 3 - 1, dc = dd - (dd / 3) * 3 - 1;
  int kr0, kr1, nr; float wr0, wr1;
  if (dr < 0)       { kr0 = 0; wr0 = 1.f; kr1 = 0; wr1 = 0.f; nr = 1; }
  else if (dr == 0) { kr0 = 1; wr0 = .5f; kr1 = 2; wr1 = .5f; nr = 2; }
  else              { kr0 = 3; wr0 = 1.f; kr1 = 0; wr1 = 0.f; nr = 1; }
  int kc0, kc1, nc; float wc0, wc1;
  if (dc < 0)       { kc0 = 0; wc0 = 1.f; kc1 = 0; wc1 = 0.f; nc = 1; }
  else if (dc == 0) { kc0 = 1; wc0 = .5f; kc1 = 2; wc1 = .5f; nc = 2; }
  else              { kc0 = 3; wc0 = 1.f; kc1 = 0; wc1 = 0.f; nc = 1; }
  float acc = wr0 * wc0 * W[(kr0 * 4 + kc0) * cinout + rem];
  if (nc == 2) acc += wr0 * wc1 * W[(kr0 * 4 + kc1) * cinout + rem];
  if (nr == 2) {
    acc += wr1 * wc0 * W[(kr1 * 4 + kc0) * cinout + rem];
    if (nc == 2) acc += wr1 * wc1 * W[(kr1 * 4 + kc1) * cinout + rem];
  }
  weff[idx] = acc;
}

// Thread = one pixel x one o-group (OC = Cout/OSPLIT outputs in registers).
// o-group is wave-uniform (readfirstlane) so weight loads are uniform -> s_load,
// making the inner loop pure v_fmac with SGPR weight operands.
template <int N, int Cin, int Cout, int OSPLIT>
__global__ __launch_bounds__(256) void conv_kernel(
    const float* __restrict__ xin, const float* __restrict__ weff,
    const float* __restrict__ root, const float* __restrict__ bias,
    float* __restrict__ out) {
  constexpr int OC = Cout / OSPLIT;
  int t = blockIdx.x * 256 + threadIdx.x;
  int lane = threadIdx.x & 63;
  int wid = t >> 6;
  int og = __builtin_amdgcn_readfirstlane(wid % OSPLIT);   // wave-uniform
  int p = (wid / OSPLIT) * 64 + lane;                      // pixel (incl. batch)
  int r = (p / N) % N;
  int c = p - (p / N) * N;
  int ib = p - (r * N + c);                                // image base node

  float acc[OC];
#pragma unroll
  for (int o = 0; o < OC; ++o) acc[o] = 0.f;

  float xn[Cin];
  float deg = 0.f;
  for (int d = 0; d < 8; ++d) {
    int dd = d >= 4 ? d + 1 : d;
    int dr = dd / 3 - 1, dc = dd - (dd / 3) * 3 - 1;
    int rr = r - dr, cc = c - dc;
    bool valid = (rr >= 0) && (rr < N) && (cc >= 0) && (cc < N);
    float m = valid ? 1.f : 0.f;
    deg += m;
    int rrc = min(max(rr, 0), N - 1), ccc = min(max(cc, 0), N - 1);
    const float* src = xin + (size_t)(ib + rrc * N + ccc) * Cin;
    if constexpr (Cin >= 4) {
#pragma unroll
      for (int i = 0; i < Cin; i += 4) {
        float4 v = *reinterpret_cast<const float4*>(src + i);
        xn[i] = v.x * m; xn[i + 1] = v.y * m;
        xn[i + 2] = v.z * m; xn[i + 3] = v.w * m;
      }
    } else {
#pragma unroll
      for (int i = 0; i < Cin; ++i) xn[i] = src[i] * m;
    }
    const float* w = weff + (size_t)d * Cin * Cout + og * OC;  // uniform addr
#pragma unroll
    for (int i = 0; i < Cin; ++i) {
      float xv = xn[i];
#pragma unroll
      for (int o = 0; o < OC; ++o)
        acc[o] = fmaf(xv, w[i * Cout + o], acc[o]);
    }
  }
  float inv = 1.f / fmaxf(deg, 1.f);
#pragma unroll
  for (int o = 0; o < OC; ++o) acc[o] *= inv;

  // root (center) term + bias + ELU
  const float* srcc = xin + (size_t)p * Cin;
  const float* rw = root + og * OC;
#pragma unroll
  for (int i = 0; i < Cin; ++i) {
    float xv = srcc[i];
#pragma unroll
    for (int o = 0; o < OC; ++o)
      acc[o] = fmaf(xv, rw[i * Cout + o], acc[o]);
  }
#pragma unroll
  for (int o = 0; o < OC; ++o) {
    float v = acc[o] + bias[og * OC + o];
    acc[o] = v > 0.f ? v : (__expf(v) - 1.f);
  }
  float* op = out + (size_t)p * Cout + og * OC;
  if constexpr (OC >= 4) {
#pragma unroll
    for (int o = 0; o < OC; o += 4) {
      float4 s = make_float4(acc[o], acc[o + 1], acc[o + 2], acc[o + 3]);
      *reinterpret_cast<float4*>(op + o) = s;
    }
  } else {
#pragma unroll
    for (int o = 0; o < OC; ++o) op[o] = acc[o];
  }
}

// 2x2 max pool (graclus factor-4 cluster == (r/2, c/2) block), channel-major inner.
template <int N, int C>
__global__ __launch_bounds__(256) void pool_kernel(
    const float* __restrict__ in, float* __restrict__ out) {
  constexpr int HN = N / 2;
  int idx = blockIdx.x * 256 + threadIdx.x;   // over B*HN*HN*C, exact grid
  int ch = idx % C;
  int pc = idx / C;
  int c2 = pc % HN;
  int r2 = (pc / HN) % HN;
  int b = pc / (HN * HN);
  const float* base = in + (size_t)((b * N + 2 * r2) * N + 2 * c2) * C + ch;
  float v = fmaxf(fmaxf(base[0], base[C]),
                  fmaxf(base[N * C], base[(N + 1) * C]));
  out[idx] = v;
}

// FC1: [256,3136] @ [3136,512], k-split into 8 partials for occupancy.
__global__ __launch_bounds__(256) void fc1_kernel(
    const float* __restrict__ x, const float* __restrict__ W,
    float* __restrict__ part) {
  constexpr int BT = 4, KSPLIT = 8, K = 3136, O = 512, KC = K / KSPLIT;  // 392
  int ks = blockIdx.x % KSPLIT;
  int bt = blockIdx.x / KSPLIT;
  int o = threadIdx.x * 2;
  int k0 = ks * KC;
  float acc[BT][2];
#pragma unroll
  for (int b = 0; b < BT; ++b) acc[b][0] = acc[b][1] = 0.f;
  for (int k = k0; k < k0 + KC; k += 4) {
    float4 xv[BT];
#pragma unroll
    for (int b = 0; b < BT; ++b)
      xv[b] = *reinterpret_cast<const float4*>(x + (size_t)(bt * BT + b) * K + k);
#pragma unroll
    for (int kk = 0; kk < 4; ++kk) {
      float2 w = *reinterpret_cast<const float2*>(W + (size_t)(k + kk) * O + o);
#pragma unroll
      for (int b = 0; b < BT; ++b) {
        float xs = kk == 0 ? xv[b].x : kk == 1 ? xv[b].y : kk == 2 ? xv[b].z : xv[b].w;
        acc[b][0] = fmaf(xs, w.x, acc[b][0]);
        acc[b][1] = fmaf(xs, w.y, acc[b][1]);
      }
    }
  }
#pragma unroll
  for (int b = 0; b < BT; ++b) {
    float2 s = make_float2(acc[b][0], acc[b][1]);
    *reinterpret_cast<float2*>(part + (size_t)(ks * 256 + bt * BT + b) * O + o) = s;
  }
}

__global__ __launch_bounds__(256) void fc1_reduce_kernel(
    const float* __restrict__ part, const float* __restrict__ bias,
    float* __restrict__ out) {
  int idx = blockIdx.x * 256 + threadIdx.x;  // 256*512 exact
  float s = 0.f;
#pragma unroll
  for (int ks = 0; ks < 8; ++ks) s += part[(size_t)ks * 131072 + idx];
  s += bias[idx & 511];
  out[idx] = s > 0.f ? s : (__expf(s) - 1.f);
}

// FC2 + log_softmax, one wave per batch row.
__global__ __launch_bounds__(64) void fc2_kernel(
    const float* __restrict__ h, const float* __restrict__ W,
    const float* __restrict__ bias, float* __restrict__ out) {
  int bb = blockIdx.x;
  int t = threadIdx.x;
  float acc[10];
#pragma unroll
  for (int o = 0; o < 10; ++o) acc[o] = 0.f;
  for (int k = t; k < 512; k += 64) {
    float xv = h[bb * 512 + k];
#pragma unroll
    for (int o = 0; o < 10; ++o)
      acc[o] = fmaf(xv, W[k * 10 + o], acc[o]);
  }
#pragma unroll
  for (int o = 0; o < 10; ++o) {
    float v = acc[o];
#pragma unroll
    for (int s = 32; s >= 1; s >>= 1) v += __shfl_xor(v, s);
    acc[o] = v + bias[o];            // every lane holds full logits after xor-reduce
  }
  float m = acc[0];
#pragma unroll
  for (int o = 1; o < 10; ++o) m = fmaxf(m, acc[o]);
  float sum = 0.f;
#pragma unroll
  for (int o = 0; o < 10; ++o) sum += __expf(acc[o] - m);
  float lse = m + __logf(sum);
  if (t < 10) out[bb * 10 + t] = acc[t] - lse;
}

extern "C" void kernel_launch(void* const* d_in, const int* in_sizes, int n_in,
                              void* d_out, int out_size, void* d_ws, size_t ws_size,
                              hipStream_t stream) {
  const float* x    = (const float*)d_in[0];
  const float* W1   = (const float*)d_in[7];
  const float* r1   = (const float*)d_in[8];
  const float* b1   = (const float*)d_in[9];
  const float* W2   = (const float*)d_in[10];
  const float* r2   = (const float*)d_in[11];
  const float* b2   = (const float*)d_in[12];
  const float* W3   = (const float*)d_in[13];
  const float* r3   = (const float*)d_in[14];
  const float* b3   = (const float*)d_in[15];
  const float* W4   = (const float*)d_in[16];
  const float* r4   = (const float*)d_in[17];
  const float* b4   = (const float*)d_in[18];
  const float* fc1W = (const float*)d_in[19];
  const float* fc1b = (const float*)d_in[20];
  const float* fc2W = (const float*)d_in[21];
  const float* fc2b = (const float*)d_in[22];
  float* ws = (float*)d_ws;

  // workspace layout (floats); two big ping-pong regions -> ~49 MB total
  float* we1 = ws;             // 8*1*32    = 256
  float* we2 = we1 + 256;      // 8*32*32   = 8192
  float* we3 = we2 + 8192;     // 8*32*64   = 16384
  float* we4 = we3 + 16384;    // 8*64*64   = 32768
  float* R1  = we4 + 32768;    // 200704*32 = 6422528
  float* R2  = R1 + 6422528;   // 6422528
  float* A1 = R1;              // conv1 out [200704,32]
  float* A2 = R2;              // conv2 out [200704,32]
  float* A3 = R1;              // pool0 out [50176,32]   (A1 dead)
  float* A4 = R2;              // conv3 out [50176,64]   (A2 dead)
  float* A5 = R1;              // conv4 out [50176,64]   (A3 dead)
  float* A6 = R2;              // pool1 out [12544,64]   (A4 dead)
  float* part = R1;            // fc1 partials [8,256,512] (A5 dead)
  float* A7 = R2 + 802816;     // fc1 out [256,512]      (after A6)

  prep_weff_kernel<<<1, 256, 0, stream>>>(W1, we1, 32);
  prep_weff_kernel<<<32, 256, 0, stream>>>(W2, we2, 1024);
  prep_weff_kernel<<<64, 256, 0, stream>>>(W3, we3, 2048);
  prep_weff_kernel<<<128, 256, 0, stream>>>(W4, we4, 4096);

  conv_kernel<28, 1, 32, 1><<<784, 256, 0, stream>>>(x, we1, r1, b1, A1);
  conv_kernel<28, 32, 32, 2><<<1568, 256, 0, stream>>>(A1, we2, r2, b2, A2);
  pool_kernel<28, 32><<<6272, 256, 0, stream>>>(A2, A3);
  conv_kernel<14, 32, 64, 4><<<784, 256, 0, stream>>>(A3, we3, r3, b3, A4);
  conv_kernel<14, 64, 64, 4><<<784, 256, 0, stream>>>(A4, we4, r4, b4, A5);
  pool_kernel<14, 64><<<3136, 256, 0, stream>>>(A5, A6);
  fc1_kernel<<<512, 256, 0, stream>>>(A6, fc1W, part);
  fc1_reduce_kernel<<<512, 256, 0, stream>>>(part, fc1b, A7);
  fc2_kernel<<<256, 64, 0, stream>>>(A7, fc2W, fc2b, (float*)d_out);
}

// Round 2
// 100.737 us; speedup vs baseline: 2.7992x; 2.7992x over previous
//
#include <hip/hip_runtime.h>

typedef unsigned short u16;
typedef short bf16x8 __attribute__((ext_vector_type(8)));   // 8 bf16 in 4 VGPRs
typedef float f32x4 __attribute__((ext_vector_type(4)));

__device__ __constant__ const int DRS[8] = {-1,-1,-1, 0, 0, 1, 1, 1};
__device__ __constant__ const int DCS[8] = {-1, 0, 1,-1, 1,-1, 0, 1};

__device__ inline float bf2f(u16 u) { return __uint_as_float(((unsigned)u) << 16); }
__device__ inline u16 f2bf(float f) {            // round-to-nearest-even
  unsigned u = __float_as_uint(f);
  return (u16)((u + 0x7fffu + ((u >> 16) & 1u)) >> 16);
}

// ---- Weff: collapse degree-1 B-spline over the 8 grid directions (fp32) ----
__global__ __launch_bounds__(256) void prep_weff_kernel(
    const float* __restrict__ W, float* __restrict__ weff, int cinout) {
  int idx = blockIdx.x * 256 + threadIdx.x;
  if (idx >= 8 * cinout) return;
  int d = idx / cinout;
  int rem = idx - d * cinout;
  int dd = d >= 4 ? d + 1 : d;          // skip (0,0)
  int dr = dd / 3 - 1, dc = dd - (dd / 3) * 3 - 1;
  int kr0, kr1, nr; float wr0, wr1;
  if (dr < 0)       { kr0 = 0; wr0 = 1.f; kr1 = 0; wr1 = 0.f; nr = 1; }
  else if (dr == 0) { kr0 = 1; wr0 = .5f; kr1 = 2; wr1 = .5f; nr = 2; }
  else              { kr0 = 3; wr0 = 1.f; kr1 = 0; wr1 = 0.f; nr = 1; }
  int kc0, kc1, nc; float wc0, wc1;
  if (dc < 0)       { kc0 = 0; wc0 = 1.f; kc1 = 0; wc1 = 0.f; nc = 1; }
  else if (dc == 0) { kc0 = 1; wc0 = .5f; kc1 = 2; wc1 = .5f; nc = 2; }
  else              { kc0 = 3; wc0 = 1.f; kc1 = 0; wc1 = 0.f; nc = 1; }
  float acc = wr0 * wc0 * W[(kr0 * 4 + kc0) * cinout + rem];
  if (nc == 2) acc += wr0 * wc1 * W[(kr0 * 4 + kc1) * cinout + rem];
  if (nr == 2) {
    acc += wr1 * wc0 * W[(kr1 * 4 + kc0) * cinout + rem];
    if (nc == 2) acc += wr1 * wc1 * W[(kr1 * 4 + kc1) * cinout + rem];
  }
  weff[idx] = acc;
}

// ---- pack Weff (+root as tap 8) into bf16 B-fragment order ----------------
// wp[((tap*CT+ct)*KQ+kcq)*512 + lane*8 + j] = W[k = kcq*32+(lane>>4)*8+j][n = ct*16+(lane&15)]
__global__ __launch_bounds__(256) void pack_kernel(
    const float* __restrict__ we2, const float* __restrict__ rt2,
    const float* __restrict__ we3, const float* __restrict__ rt3,
    const float* __restrict__ we4, const float* __restrict__ rt4,
    u16* __restrict__ wp2, u16* __restrict__ wp3, u16* __restrict__ wp4) {
  int idx = blockIdx.x * 256 + threadIdx.x;
  const float *we, *rt; u16* wp; int cin, cout, ctn, kcn, local;
  if (idx < 9216)       { we = we2; rt = rt2; wp = wp2; cin = 32; cout = 32; ctn = 2; kcn = 1; local = idx; }
  else if (idx < 27648) { we = we3; rt = rt3; wp = wp3; cin = 32; cout = 64; ctn = 4; kcn = 1; local = idx - 9216; }
  else if (idx < 64512) { we = we4; rt = rt4; wp = wp4; cin = 64; cout = 64; ctn = 4; kcn = 2; local = idx - 27648; }
  else return;
  int j = local & 7, lane = (local >> 3) & 63, chunk = local >> 9;
  int kcq = chunk % kcn;
  int ct = (chunk / kcn) % ctn;
  int tap = chunk / (kcn * ctn);
  int k = kcq * 32 + (lane >> 4) * 8 + j;
  int n = ct * 16 + (lane & 15);
  float v = (tap < 8) ? we[(tap * cin + k) * cout + n] : rt[k * cout + n];
  wp[local] = f2bf(v);
}

// ---- conv1: Cin=1, fp32 compute, bf16 store --------------------------------
__global__ __launch_bounds__(256) void conv1_kernel(
    const float* __restrict__ x, const float* __restrict__ weff,
    const float* __restrict__ root, const float* __restrict__ bias,
    u16* __restrict__ out) {
  int p = blockIdx.x * 256 + threadIdx.x;            // < 200704 exact
  int pr = (p / 28) % 28, pc = p % 28;
  int ib = p - pr * 28 - pc;
  float acc[32];
#pragma unroll
  for (int o = 0; o < 32; ++o) acc[o] = 0.f;
  float deg = 0.f;
#pragma unroll
  for (int d = 0; d < 8; ++d) {
    int rr = pr - DRS[d], cc = pc - DCS[d];
    bool ok = (rr >= 0) && (rr < 28) && (cc >= 0) && (cc < 28);
    int rc = min(max(rr, 0), 27), ccl = min(max(cc, 0), 27);
    float xv = ok ? x[ib + rc * 28 + ccl] : 0.f;
    deg += ok ? 1.f : 0.f;
#pragma unroll
    for (int o = 0; o < 32; ++o) acc[o] = fmaf(xv, weff[d * 32 + o], acc[o]);
  }
  float inv = 1.f / deg;
  float xc = x[p];
  unsigned pk[16];
#pragma unroll
  for (int o2 = 0; o2 < 16; ++o2) {
    float v0 = acc[2 * o2] * inv + xc * root[2 * o2] + bias[2 * o2];
    float v1 = acc[2 * o2 + 1] * inv + xc * root[2 * o2 + 1] + bias[2 * o2 + 1];
    v0 = v0 > 0.f ? v0 : (__expf(v0) - 1.f);
    v1 = v1 > 0.f ? v1 : (__expf(v1) - 1.f);
    pk[o2] = (unsigned)f2bf(v0) | ((unsigned)f2bf(v1) << 16);
  }
#pragma unroll
  for (int q = 0; q < 4; ++q) {
    int4 s = make_int4(pk[4 * q], pk[4 * q + 1], pk[4 * q + 2], pk[4 * q + 3]);
    *reinterpret_cast<int4*>(out + (size_t)p * 32 + q * 8) = s;
  }
}

// ---- MFMA conv: block = 1 image, zero-padded LDS tile, 9 shifted taps ------
template <int NIMG, int CIN, int COUT>
__global__ __launch_bounds__(512) void mfma_conv(
    const u16* __restrict__ xin, const u16* __restrict__ wp,
    const float* __restrict__ bias, u16* __restrict__ out) {
  constexpr int PIX = NIMG * NIMG;
  constexpr int PR = NIMG + 2;
  constexpr int PC = (NIMG == 28) ? 32 : 16;
  constexpr int KCN = CIN / 8;          // 16B chunks per pixel
  constexpr int KQ = CIN / 32;          // k-chunks per MFMA chain
  constexpr int CT = COUT / 16;
  constexpr int NCT = (NIMG == 28) ? 2 : 1;  // cout-tiles per wave
  constexpr int NTILE = (PIX + 15) / 16;
  constexpr int KSH = (KCN == 4) ? 2 : 3;
  constexpr int LDSN = KCN * PR * PC;

  __shared__ int4 lds[LDSN];

  int img = blockIdx.x;
  int tid = threadIdx.x;
  int lane = tid & 63, wid = tid >> 6;

  int ctg, t0, ts;
  if constexpr (NCT == 2) { ctg = 0; t0 = wid; ts = 8; }
  else { ctg = wid & 3; t0 = wid >> 2; ts = 2; }

  // B-fragments to registers (global, L2-hot, coalesced 16B/lane)
  bf16x8 wB[9][KQ][NCT];
#pragma unroll
  for (int tap = 0; tap < 9; ++tap)
#pragma unroll
    for (int q = 0; q < KQ; ++q)
#pragma unroll
      for (int cc = 0; cc < NCT; ++cc)
        wB[tap][q][cc] = *reinterpret_cast<const bf16x8*>(
            wp + ((size_t)((tap * CT + ctg + cc) * KQ + q) * 64 + lane) * 8);

  // stage: zero pad + interior fill
  for (int i = tid; i < LDSN; i += 512) lds[i] = make_int4(0, 0, 0, 0);
  __syncthreads();
  for (int i = tid; i < PIX * KCN; i += 512) {
    int kc = i & (KCN - 1);
    int px = i >> KSH;
    int r = px / NIMG, c = px % NIMG;
    lds[(kc * PR + r + 1) * PC + (c + 1)] =
        *reinterpret_cast<const int4*>(xin + ((size_t)img * PIX + px) * CIN + kc * 8);
  }
  __syncthreads();

  int kcb = lane >> 4;
  int n0 = lane & 15;
  for (int t = t0; t < NTILE; t += ts) {
    int pxm = t * 16 + n0;
    if (pxm > PIX - 1) pxm = PIX - 1;          // partial-tile clamp (reads only)
    int r = pxm / NIMG, c = pxm % NIMG;
    f32x4 accn[NCT], accr[NCT];
    f32x4 zz = {0.f, 0.f, 0.f, 0.f};
#pragma unroll
    for (int cc = 0; cc < NCT; ++cc) { accn[cc] = zz; accr[cc] = zz; }
#pragma unroll
    for (int d = 0; d < 8; ++d) {
      int rr = r - DRS[d] + 1, c2 = c - DCS[d] + 1;
#pragma unroll
      for (int q = 0; q < KQ; ++q) {
        bf16x8 a = *reinterpret_cast<const bf16x8*>(
            &lds[((q * 4 + kcb) * PR + rr) * PC + c2]);
#pragma unroll
        for (int cc = 0; cc < NCT; ++cc)
          accn[cc] = __builtin_amdgcn_mfma_f32_16x16x32_bf16(a, wB[d][q][cc], accn[cc], 0, 0, 0);
      }
    }
    {   // root tap (center, not degree-normalized)
      int rr = r + 1, c2 = c + 1;
#pragma unroll
      for (int q = 0; q < KQ; ++q) {
        bf16x8 a = *reinterpret_cast<const bf16x8*>(
            &lds[((q * 4 + kcb) * PR + rr) * PC + c2]);
#pragma unroll
        for (int cc = 0; cc < NCT; ++cc)
          accr[cc] = __builtin_amdgcn_mfma_f32_16x16x32_bf16(a, wB[8][q][cc], accr[cc], 0, 0, 0);
      }
    }
    // epilogue: D map row=(lane>>4)*4+j, col=lane&15  [m89-verified]
#pragma unroll
    for (int j = 0; j < 4; ++j) {
      int pm = t * 16 + (lane >> 4) * 4 + j;
      if (pm < PIX) {
        int rm = pm / NIMG, cm = pm % NIMG;
        float dg = (float)((3 - (rm == 0) - (rm == NIMG - 1)) *
                           (3 - (cm == 0) - (cm == NIMG - 1)) - 1);
        float inv = 1.f / dg;
#pragma unroll
        for (int cc = 0; cc < NCT; ++cc) {
          int n = (ctg + cc) * 16 + n0;
          float v = accn[cc][j] * inv + accr[cc][j] + bias[n];
          v = v > 0.f ? v : (__expf(v) - 1.f);
          out[((size_t)img * PIX + pm) * COUT + n] = f2bf(v);
        }
      }
    }
  }
}

// ---- 2x2 max pool, bf16 -> bf16 --------------------------------------------
template <int NIN, int C>
__global__ __launch_bounds__(256) void pool_bf16(
    const u16* __restrict__ in, u16* __restrict__ out) {
  constexpr int KC = C / 8, HN = NIN / 2, OP = HN * HN;
  int idx = blockIdx.x * 256 + threadIdx.x;
  int kc = idx & (KC - 1);
  int q = idx >> ((KC == 4) ? 2 : 3);
  int b = q / OP, qq = q % OP;
  int r2 = qq / HN, c2 = qq % HN;
  size_t ib = ((size_t)b * NIN * NIN + (2 * r2) * NIN + 2 * c2) * C + kc * 8;
  int4 v00 = *reinterpret_cast<const int4*>(in + ib);
  int4 v01 = *reinterpret_cast<const int4*>(in + ib + C);
  int4 v10 = *reinterpret_cast<const int4*>(in + ib + (size_t)NIN * C);
  int4 v11 = *reinterpret_cast<const int4*>(in + ib + (size_t)(NIN + 1) * C);
  const u16* a = (const u16*)&v00; const u16* bb = (const u16*)&v01;
  const u16* cc = (const u16*)&v10; const u16* dd = (const u16*)&v11;
  union { int4 v; u16 s[8]; } R;
#pragma unroll
  for (int e = 0; e < 8; ++e) {
    float m = fmaxf(fmaxf(bf2f(a[e]), bf2f(bb[e])), fmaxf(bf2f(cc[e]), bf2f(dd[e])));
    R.s[e] = f2bf(m);
  }
  *reinterpret_cast<int4*>(out + (size_t)q * C + kc * 8) = R.v;
}

// ---- 2x2 max pool, bf16 -> fp32 (feeds fp32 FC path) ----------------------
__global__ __launch_bounds__(256) void pool1_kernel(
    const u16* __restrict__ in, float* __restrict__ out) {
  int idx = blockIdx.x * 256 + threadIdx.x;        // 100352 exact
  int kc = idx & 7;
  int q = idx >> 3;
  int b = q / 49, qq = q % 49;
  int r2 = qq / 7, c2 = qq % 7;
  size_t ib = ((size_t)b * 196 + (2 * r2) * 14 + 2 * c2) * 64 + kc * 8;
  int4 v00 = *reinterpret_cast<const int4*>(in + ib);
  int4 v01 = *reinterpret_cast<const int4*>(in + ib + 64);
  int4 v10 = *reinterpret_cast<const int4*>(in + ib + 14 * 64);
  int4 v11 = *reinterpret_cast<const int4*>(in + ib + 15 * 64);
  const u16* a = (const u16*)&v00; const u16* bb = (const u16*)&v01;
  const u16* cc = (const u16*)&v10; const u16* dd = (const u16*)&v11;
  float m[8];
#pragma unroll
  for (int e = 0; e < 8; ++e)
    m[e] = fmaxf(fmaxf(bf2f(a[e]), bf2f(bb[e])), fmaxf(bf2f(cc[e]), bf2f(dd[e])));
  float* op = out + (size_t)q * 64 + kc * 8;
  *reinterpret_cast<float4*>(op) = make_float4(m[0], m[1], m[2], m[3]);
  *reinterpret_cast<float4*>(op + 4) = make_float4(m[4], m[5], m[6], m[7]);
}

// ---- FC1 (fp32, k-split 8) + reduce + FC2/log_softmax (unchanged, proven) --
__global__ __launch_bounds__(256) void fc1_kernel(
    const float* __restrict__ x, const float* __restrict__ W,
    float* __restrict__ part) {
  constexpr int BT = 4, KSPLIT = 8, K = 3136, O = 512, KC = K / KSPLIT;
  int ks = blockIdx.x % KSPLIT;
  int bt = blockIdx.x / KSPLIT;
  int o = threadIdx.x * 2;
  int k0 = ks * KC;
  float acc[BT][2];
#pragma unroll
  for (int b = 0; b < BT; ++b) acc[b][0] = acc[b][1] = 0.f;
  for (int k = k0; k < k0 + KC; k += 4) {
    float4 xv[BT];
#pragma unroll
    for (int b = 0; b < BT; ++b)
      xv[b] = *reinterpret_cast<const float4*>(x + (size_t)(bt * BT + b) * K + k);
#pragma unroll
    for (int kk = 0; kk < 4; ++kk) {
      float2 w = *reinterpret_cast<const float2*>(W + (size_t)(k + kk) * O + o);
#pragma unroll
      for (int b = 0; b < BT; ++b) {
        float xs = kk == 0 ? xv[b].x : kk == 1 ? xv[b].y : kk == 2 ? xv[b].z : xv[b].w;
        acc[b][0] = fmaf(xs, w.x, acc[b][0]);
        acc[b][1] = fmaf(xs, w.y, acc[b][1]);
      }
    }
  }
#pragma unroll
  for (int b = 0; b < BT; ++b) {
    float2 s = make_float2(acc[b][0], acc[b][1]);
    *reinterpret_cast<float2*>(part + (size_t)(ks * 256 + bt * BT + b) * O + o) = s;
  }
}

__global__ __launch_bounds__(256) void fc1_reduce_kernel(
    const float* __restrict__ part, const float* __restrict__ bias,
    float* __restrict__ out) {
  int idx = blockIdx.x * 256 + threadIdx.x;
  float s = 0.f;
#pragma unroll
  for (int ks = 0; ks < 8; ++ks) s += part[(size_t)ks * 131072 + idx];
  s += bias[idx & 511];
  out[idx] = s > 0.f ? s : (__expf(s) - 1.f);
}

__global__ __launch_bounds__(64) void fc2_kernel(
    const float* __restrict__ h, const float* __restrict__ W,
    const float* __restrict__ bias, float* __restrict__ out) {
  int bb = blockIdx.x;
  int t = threadIdx.x;
  float acc[10];
#pragma unroll
  for (int o = 0; o < 10; ++o) acc[o] = 0.f;
  for (int k = t; k < 512; k += 64) {
    float xv = h[bb * 512 + k];
#pragma unroll
    for (int o = 0; o < 10; ++o)
      acc[o] = fmaf(xv, W[k * 10 + o], acc[o]);
  }
#pragma unroll
  for (int o = 0; o < 10; ++o) {
    float v = acc[o];
#pragma unroll
    for (int s = 32; s >= 1; s >>= 1) v += __shfl_xor(v, s);
    acc[o] = v + bias[o];
  }
  float m = acc[0];
#pragma unroll
  for (int o = 1; o < 10; ++o) m = fmaxf(m, acc[o]);
  float sum = 0.f;
#pragma unroll
  for (int o = 0; o < 10; ++o) sum += __expf(acc[o] - m);
  float lse = m + __logf(sum);
  if (t < 10) out[bb * 10 + t] = acc[t] - lse;
}

extern "C" void kernel_launch(void* const* d_in, const int* in_sizes, int n_in,
                              void* d_out, int out_size, void* d_ws, size_t ws_size,
                              hipStream_t stream) {
  const float* x    = (const float*)d_in[0];
  const float* W1   = (const float*)d_in[7];
  const float* r1   = (const float*)d_in[8];
  const float* b1   = (const float*)d_in[9];
  const float* W2   = (const float*)d_in[10];
  const float* r2   = (const float*)d_in[11];
  const float* b2   = (const float*)d_in[12];
  const float* W3   = (const float*)d_in[13];
  const float* r3   = (const float*)d_in[14];
  const float* b3   = (const float*)d_in[15];
  const float* W4   = (const float*)d_in[16];
  const float* r4   = (const float*)d_in[17];
  const float* b4   = (const float*)d_in[18];
  const float* fc1W = (const float*)d_in[19];
  const float* fc1b = (const float*)d_in[20];
  const float* fc2W = (const float*)d_in[21];
  const float* fc2b = (const float*)d_in[22];
  float* ws = (float*)d_ws;

  // workspace layout (float offsets)
  float* we1 = ws + 0;               // 8*32
  float* we2 = ws + 256;             // 8*1024
  float* we3 = ws + 8448;            // 8*2048
  float* we4 = ws + 24832;           // 8*4096
  u16* wp2   = (u16*)(ws + 57600);   // 9216 bf16
  u16* wp3   = (u16*)(ws + 62208);   // 18432 bf16
  u16* wp4   = (u16*)(ws + 71424);   // 36864 bf16
  u16* A1    = (u16*)(ws + 89856);   // [200704,32] bf16
  u16* A2    = (u16*)(ws + 3301120); // [200704,32] bf16
  u16* A3    = (u16*)(ws + 6512384); // [50176,32]  bf16
  u16* A4    = (u16*)(ws + 7315200); // [50176,64]  bf16
  u16* A5    = (u16*)(ws + 8920832); // [50176,64]  bf16
  float* A6  = ws + 10526464;        // [12544,64]  fp32
  float* part= ws + 11329280;        // [8,256,512] fp32
  float* A7  = ws + 12377856;        // [256,512]   fp32

  prep_weff_kernel<<<1, 256, 0, stream>>>(W1, we1, 32);
  prep_weff_kernel<<<32, 256, 0, stream>>>(W2, we2, 1024);
  prep_weff_kernel<<<64, 256, 0, stream>>>(W3, we3, 2048);
  prep_weff_kernel<<<128, 256, 0, stream>>>(W4, we4, 4096);
  pack_kernel<<<252, 256, 0, stream>>>(we2, r2, we3, r3, we4, r4, wp2, wp3, wp4);

  conv1_kernel<<<784, 256, 0, stream>>>(x, we1, r1, b1, A1);
  mfma_conv<28, 32, 32><<<256, 512, 0, stream>>>(A1, wp2, b2, A2);
  pool_bf16<28, 32><<<784, 256, 0, stream>>>(A2, A3);
  mfma_conv<14, 32, 64><<<256, 512, 0, stream>>>(A3, wp3, b3, A4);
  mfma_conv<14, 64, 64><<<256, 512, 0, stream>>>(A4, wp4, b4, A5);
  pool1_kernel<<<392, 256, 0, stream>>>(A5, A6);

  fc1_kernel<<<512, 256, 0, stream>>>(A6, fc1W, part);
  fc1_reduce_kernel<<<512, 256, 0, stream>>>(part, fc1b, A7);
  fc2_kernel<<<256, 64, 0, stream>>>(A7, fc2W, fc2b, (float*)d_out);
}

// Round 3
// 62.138 us; speedup vs baseline: 4.5381x; 1.6212x over previous
//
#include <hip/hip_runtime.h>

typedef unsigned short u16;
typedef short bf16x8 __attribute__((ext_vector_type(8)));   // 8 bf16 in 4 VGPRs
typedef float f32x4 __attribute__((ext_vector_type(4)));

__device__ __constant__ const int DRS[8] = {-1,-1,-1, 0, 0, 1, 1, 1};
__device__ __constant__ const int DCS[8] = {-1, 0, 1,-1, 1,-1, 0, 1};

__device__ inline float bf2f(u16 u) { return __uint_as_float(((unsigned)u) << 16); }
__device__ inline u16 f2bf(float f) {            // round-to-nearest-even
  unsigned u = __float_as_uint(f);
  return (u16)((u + 0x7fffu + ((u >> 16) & 1u)) >> 16);
}
__device__ inline float eluf(float v) { return v > 0.f ? v : (__expf(v) - 1.f); }

// collapse degree-1 B-spline weights for grid direction d (0..7, center skipped)
__device__ inline float weff_val(const float* __restrict__ W, int d, int off, int stride) {
  int dd = d >= 4 ? d + 1 : d;
  int dr = dd / 3 - 1, dc = dd - (dd / 3) * 3 - 1;
  int kr0, kr1, nr; float wr0, wr1;
  if (dr < 0)       { kr0 = 0; wr0 = 1.f; kr1 = 0; wr1 = 0.f; nr = 1; }
  else if (dr == 0) { kr0 = 1; wr0 = .5f; kr1 = 2; wr1 = .5f; nr = 2; }
  else              { kr0 = 3; wr0 = 1.f; kr1 = 0; wr1 = 0.f; nr = 1; }
  int kc0, kc1, nc; float wc0, wc1;
  if (dc < 0)       { kc0 = 0; wc0 = 1.f; kc1 = 0; wc1 = 0.f; nc = 1; }
  else if (dc == 0) { kc0 = 1; wc0 = .5f; kc1 = 2; wc1 = .5f; nc = 2; }
  else              { kc0 = 3; wc0 = 1.f; kc1 = 0; wc1 = 0.f; nc = 1; }
  float acc = wr0 * wc0 * W[(kr0 * 4 + kc0) * stride + off];
  if (nc == 2) acc += wr0 * wc1 * W[(kr0 * 4 + kc1) * stride + off];
  if (nr == 2) {
    acc += wr1 * wc0 * W[(kr1 * 4 + kc0) * stride + off];
    if (nc == 2) acc += wr1 * wc1 * W[(kr1 * 4 + kc1) * stride + off];
  }
  return acc;
}

// ---- single prep kernel: weff1 (fp32) + wp2/3/4 (bf16 B-frags) + fc1W pack --
__global__ __launch_bounds__(256) void pack_all(
    const float* __restrict__ W1,
    const float* __restrict__ W2, const float* __restrict__ rt2,
    const float* __restrict__ W3, const float* __restrict__ rt3,
    const float* __restrict__ W4, const float* __restrict__ rt4,
    const float* __restrict__ fcW,
    float* __restrict__ wf1, u16* __restrict__ wp2,
    u16* __restrict__ wp3, u16* __restrict__ wp4, u16* __restrict__ wfc) {
  int idx = blockIdx.x * 256 + threadIdx.x;
  if (idx < 256) {                                   // weff1 fp32 [8][32]
    int d = idx >> 5, o = idx & 31;
    wf1[idx] = weff_val(W1, d, o, 32);
    return;
  }
  if (idx < 9472) {                                  // wp2: CT=2 KQ=1 (cin32,cout32)
    int local = idx - 256;
    int j = local & 7, l = (local >> 3) & 63, chunk = local >> 9;
    int ct = chunk & 1, tap = chunk >> 1;
    int k = (l >> 4) * 8 + j, n = ct * 16 + (l & 15);
    float v = tap < 8 ? weff_val(W2, tap, k * 32 + n, 1024) : rt2[k * 32 + n];
    wp2[local] = f2bf(v);
    return;
  }
  if (idx < 27904) {                                 // wp3: CT=4 KQ=1 (cin32,cout64)
    int local = idx - 9472;
    int j = local & 7, l = (local >> 3) & 63, chunk = local >> 9;
    int ct = chunk & 3, tap = chunk >> 2;
    int k = (l >> 4) * 8 + j, n = ct * 16 + (l & 15);
    float v = tap < 8 ? weff_val(W3, tap, k * 64 + n, 2048) : rt3[k * 64 + n];
    wp3[local] = f2bf(v);
    return;
  }
  if (idx < 64768) {                                 // wp4: CT=4 KQ=2 (cin64,cout64)
    int local = idx - 27904;
    int j = local & 7, l = (local >> 3) & 63, chunk = local >> 9;
    int q = chunk & 1, tmp = chunk >> 1;
    int ct = tmp & 3, tap = tmp >> 2;
    int k = q * 32 + (l >> 4) * 8 + j, n = ct * 16 + (l & 15);
    float v = tap < 8 ? weff_val(W4, tap, k * 64 + n, 4096) : rt4[k * 64 + n];
    wp4[local] = f2bf(v);
    return;
  }
  {                                                  // wfc: fc1_W bf16 B-frags
    int local = idx - 64768;                         // < 1605632
    int j = local & 7, l = (local >> 3) & 63, qnt = local >> 9;
    int q = qnt >> 5, nt = qnt & 31;
    int k = q * 32 + (l >> 4) * 8 + j;
    int n = nt * 16 + (l & 15);
    wfc[local] = f2bf(fcW[(size_t)k * 512 + n]);
  }
}

// ---- mega conv kernel: block = 1 image, whole conv stack LDS-resident ------
// LDS map (bytes):
//   H1 @0      : conv1 out, 4 groups stride 962 int4 (skew 8 banks) = 61568 B
//   H3 @0      : pool0 out, 4 groups stride 258 int4 = 16512 B  (H1 dead)
//   H5 @17408  : conv4 out [196][64] u16 = 25088 B              (H1 dead)
//   XT @61568  : x tile [30][32] f32 = 3840 B
//   H2 @61568  : conv2 out [784][4] int4 = 50176 B              (XT dead)
//   H4 @61568  : conv3 out, 8 groups stride 258 int4 = 33024 B  (H2 dead)
// total dynamic = 61568 + 50176 = 111744 B
__global__ __launch_bounds__(512) void conv_mega(
    const float* __restrict__ x,
    const float* __restrict__ wf1, const float* __restrict__ rt1, const float* __restrict__ b1,
    const u16* __restrict__ wp2, const float* __restrict__ b2,
    const u16* __restrict__ wp3, const float* __restrict__ b3,
    const u16* __restrict__ wp4, const float* __restrict__ b4,
    u16* __restrict__ A6) {
  extern __shared__ char smem[];
  int4* H1 = (int4*)smem;
  int4* H3 = (int4*)smem;
  u16*  H5 = (u16*)(smem + 17408);
  float* XT = (float*)(smem + 61568);
  int4* H2 = (int4*)(smem + 61568);
  u16*  H2u = (u16*)(smem + 61568);
  int4* H4 = (int4*)(smem + 61568);
  u16*  H4u = (u16*)(smem + 61568);

  int img = blockIdx.x, tid = threadIdx.x;
  int lane = tid & 63, wid = tid >> 6;
  int kcb = lane >> 4, n0 = lane & 15;
  int4 z4 = make_int4(0, 0, 0, 0);

  // conv2 weights early (L2-hot broadcast)
  bf16x8 w2[9][2];
#pragma unroll
  for (int tap = 0; tap < 9; ++tap)
#pragma unroll
    for (int cc = 0; cc < 2; ++cc)
      w2[tap][cc] = *(const bf16x8*)(wp2 + (tap * 2 + cc) * 512 + lane * 8);

  // zero H1 pads + XT, then load x tile
  for (int i = tid; i < 3848; i += 512) H1[i] = z4;
  for (int i = tid; i < 960; i += 512) XT[i] = 0.f;
  __syncthreads();
  for (int i = tid; i < 784; i += 512) {
    int r = i / 28, c = i - 28 * (i / 28);
    XT[(r + 1) * 32 + c + 1] = x[(size_t)img * 784 + i];
  }
  __syncthreads();

  // ---- conv1 (Cin=1, fp32) -> H1 bf16 chunks ----
  for (int px = tid; px < 784; px += 512) {
    int r = px / 28, c = px - 28 * (px / 28);
    float acc[32];
#pragma unroll
    for (int o = 0; o < 32; ++o) acc[o] = 0.f;
#pragma unroll
    for (int d = 0; d < 8; ++d) {
      float xv = XT[(r + 1 - DRS[d]) * 32 + (c + 1 - DCS[d])];
#pragma unroll
      for (int o = 0; o < 32; ++o) acc[o] = fmaf(xv, wf1[d * 32 + o], acc[o]);
    }
    float inv = 1.f / (float)((3 - (r == 0) - (r == 27)) * (3 - (c == 0) - (c == 27)) - 1);
    float xc = XT[(r + 1) * 32 + c + 1];
    unsigned pk[16];
#pragma unroll
    for (int h = 0; h < 16; ++h) {
      float v0 = eluf(acc[2 * h] * inv + xc * rt1[2 * h] + b1[2 * h]);
      float v1 = eluf(acc[2 * h + 1] * inv + xc * rt1[2 * h + 1] + b1[2 * h + 1]);
      pk[h] = (unsigned)f2bf(v0) | ((unsigned)f2bf(v1) << 16);
    }
#pragma unroll
    for (int kc = 0; kc < 4; ++kc)
      H1[kc * 962 + (r + 1) * 32 + (c + 1)] =
          make_int4(pk[4 * kc], pk[4 * kc + 1], pk[4 * kc + 2], pk[4 * kc + 3]);
  }
  __syncthreads();

  // ---- conv2 (32->32, MFMA) H1 -> H2 ----
  for (int t = wid; t < 49; t += 8) {
    int pxm = t * 16 + n0;
    int r = pxm / 28, c = pxm - 28 * (pxm / 28);
    f32x4 an0 = {0,0,0,0}, an1 = {0,0,0,0}, ar0 = {0,0,0,0}, ar1 = {0,0,0,0};
#pragma unroll
    for (int d = 0; d < 8; ++d) {
      bf16x8 a = *(const bf16x8*)&H1[kcb * 962 + (r + 1 - DRS[d]) * 32 + (c + 1 - DCS[d])];
      an0 = __builtin_amdgcn_mfma_f32_16x16x32_bf16(a, w2[d][0], an0, 0, 0, 0);
      an1 = __builtin_amdgcn_mfma_f32_16x16x32_bf16(a, w2[d][1], an1, 0, 0, 0);
    }
    {
      bf16x8 a = *(const bf16x8*)&H1[kcb * 962 + (r + 1) * 32 + (c + 1)];
      ar0 = __builtin_amdgcn_mfma_f32_16x16x32_bf16(a, w2[8][0], ar0, 0, 0, 0);
      ar1 = __builtin_amdgcn_mfma_f32_16x16x32_bf16(a, w2[8][1], ar1, 0, 0, 0);
    }
#pragma unroll
    for (int j = 0; j < 4; ++j) {
      int pm = t * 16 + (lane >> 4) * 4 + j;
      int rm = pm / 28, cm = pm - 28 * (pm / 28);
      float inv = 1.f / (float)((3 - (rm == 0) - (rm == 27)) * (3 - (cm == 0) - (cm == 27)) - 1);
      H2u[pm * 32 + n0]      = f2bf(eluf(an0[j] * inv + ar0[j] + b2[n0]));
      H2u[pm * 32 + 16 + n0] = f2bf(eluf(an1[j] * inv + ar1[j] + b2[16 + n0]));
    }
  }
  __syncthreads();

  // ---- pool0: H2 [784][32] -> H3 padded (writes pads = 0) ----
  for (int i = tid; i < 1032; i += 512) {
    int kc = i / 258, rem = i - 258 * kc;
    int4 v = z4;
    if (rem < 256) {
      int pr = rem >> 4, pc = rem & 15;
      if (pr >= 1 && pr <= 14 && pc >= 1 && pc <= 14) {
        int px0 = (2 * (pr - 1)) * 28 + 2 * (pc - 1);
        union { int4 q; u16 s[8]; } A, B, C, D, R;
        A.q = H2[px0 * 4 + kc]; B.q = H2[(px0 + 1) * 4 + kc];
        C.q = H2[(px0 + 28) * 4 + kc]; D.q = H2[(px0 + 29) * 4 + kc];
#pragma unroll
        for (int e = 0; e < 8; ++e)
          R.s[e] = f2bf(fmaxf(fmaxf(bf2f(A.s[e]), bf2f(B.s[e])),
                              fmaxf(bf2f(C.s[e]), bf2f(D.s[e]))));
        v = R.q;
      }
    }
    H3[i] = v;
  }
  __syncthreads();

  // ---- conv3 (32->64, MFMA) H3 -> H4 ----
  int ctg = wid & 3, t0 = wid >> 2;
  bf16x8 w3[9];
#pragma unroll
  for (int tap = 0; tap < 9; ++tap)
    w3[tap] = *(const bf16x8*)(wp3 + (tap * 4 + ctg) * 512 + lane * 8);
  for (int i = tid; i < 2064; i += 512) H4[i] = z4;   // zero H4 (H2 dead)
  __syncthreads();

  for (int t = t0; t < 13; t += 2) {
    int pxm = t * 16 + n0; if (pxm > 195) pxm = 195;
    int r = pxm / 14, c = pxm - 14 * (pxm / 14);
    f32x4 an = {0,0,0,0}, ar = {0,0,0,0};
#pragma unroll
    for (int d = 0; d < 8; ++d) {
      bf16x8 a = *(const bf16x8*)&H3[kcb * 258 + (r + 1 - DRS[d]) * 16 + (c + 1 - DCS[d])];
      an = __builtin_amdgcn_mfma_f32_16x16x32_bf16(a, w3[d], an, 0, 0, 0);
    }
    {
      bf16x8 a = *(const bf16x8*)&H3[kcb * 258 + (r + 1) * 16 + (c + 1)];
      ar = __builtin_amdgcn_mfma_f32_16x16x32_bf16(a, w3[8], ar, 0, 0, 0);
    }
#pragma unroll
    for (int j = 0; j < 4; ++j) {
      int pm = t * 16 + (lane >> 4) * 4 + j;
      if (pm < 196) {
        int rm = pm / 14, cm = pm - 14 * (pm / 14);
        float inv = 1.f / (float)((3 - (rm == 0) - (rm == 13)) * (3 - (cm == 0) - (cm == 13)) - 1);
        int n = ctg * 16 + n0;
        float v = eluf(an[j] * inv + ar[j] + b3[n]);
        H4u[((n >> 3) * 258 + (rm + 1) * 16 + (cm + 1)) * 8 + (n & 7)] = f2bf(v);
      }
    }
  }
  __syncthreads();

  // ---- conv4 (64->64, MFMA, KQ=2) H4 -> H5 ----
  bf16x8 w4[9][2];
#pragma unroll
  for (int tap = 0; tap < 9; ++tap)
#pragma unroll
    for (int q = 0; q < 2; ++q)
      w4[tap][q] = *(const bf16x8*)(wp4 + ((tap * 4 + ctg) * 2 + q) * 512 + lane * 8);

  for (int t = t0; t < 13; t += 2) {
    int pxm = t * 16 + n0; if (pxm > 195) pxm = 195;
    int r = pxm / 14, c = pxm - 14 * (pxm / 14);
    f32x4 an = {0,0,0,0}, ar = {0,0,0,0};
#pragma unroll
    for (int d = 0; d < 8; ++d) {
      int rr = r + 1 - DRS[d], c2 = c + 1 - DCS[d];
#pragma unroll
      for (int q = 0; q < 2; ++q) {
        bf16x8 a = *(const bf16x8*)&H4[(q * 4 + kcb) * 258 + rr * 16 + c2];
        an = __builtin_amdgcn_mfma_f32_16x16x32_bf16(a, w4[d][q], an, 0, 0, 0);
      }
    }
    {
#pragma unroll
      for (int q = 0; q < 2; ++q) {
        bf16x8 a = *(const bf16x8*)&H4[(q * 4 + kcb) * 258 + (r + 1) * 16 + (c + 1)];
        ar = __builtin_amdgcn_mfma_f32_16x16x32_bf16(a, w4[8][q], ar, 0, 0, 0);
      }
    }
#pragma unroll
    for (int j = 0; j < 4; ++j) {
      int pm = t * 16 + (lane >> 4) * 4 + j;
      if (pm < 196) {
        int rm = pm / 14, cm = pm - 14 * (pm / 14);
        float inv = 1.f / (float)((3 - (rm == 0) - (rm == 13)) * (3 - (cm == 0) - (cm == 13)) - 1);
        int n = ctg * 16 + n0;
        H5[pm * 64 + n] = f2bf(eluf(an[j] * inv + ar[j] + b4[n]));
      }
    }
  }
  __syncthreads();

  // ---- pool1: H5 [196][64] -> global A6 [img][49*64] bf16 ----
  if (tid < 392) {
    int kc = tid & 7, q = tid >> 3;
    int r2 = q / 7, c2 = q - 7 * (q / 7);
    int px0 = (2 * r2) * 14 + 2 * c2;
    union { int4 q4; u16 s[8]; } A, B, C, D, R;
    A.q4 = *(const int4*)&H5[px0 * 64 + kc * 8];
    B.q4 = *(const int4*)&H5[(px0 + 1) * 64 + kc * 8];
    C.q4 = *(const int4*)&H5[(px0 + 14) * 64 + kc * 8];
    D.q4 = *(const int4*)&H5[(px0 + 15) * 64 + kc * 8];
#pragma unroll
    for (int e = 0; e < 8; ++e)
      R.s[e] = f2bf(fmaxf(fmaxf(bf2f(A.s[e]), bf2f(B.s[e])),
                          fmaxf(bf2f(C.s[e]), bf2f(D.s[e]))));
    *(int4*)(A6 + ((size_t)img * 49 + q) * 64 + kc * 8) = R.q4;
  }
}

// ---- FC1 bf16 MFMA: [256,3136]x[3136,512], k-split 7, 64x64 tiles ----------
__global__ __launch_bounds__(256) void fc1_mfma(
    const u16* __restrict__ A6, const u16* __restrict__ wfc,
    float* __restrict__ part) {
  int blk = blockIdx.x;              // 224 = 7 ks x 4 mt x 8 nt
  int ks = blk % 7;
  int mn = blk / 7;
  int mt = mn & 3, nt = mn >> 2;
  int lane = threadIdx.x & 63, w = threadIdx.x >> 6;
  int n16 = nt * 4 + w;
  f32x4 acc[4];
#pragma unroll
  for (int m4 = 0; m4 < 4; ++m4) acc[m4] = {0.f, 0.f, 0.f, 0.f};
  int rbase = mt * 64 + (lane & 15);
  int kb = ks * 448 + (lane >> 4) * 8;
  for (int qq = 0; qq < 14; ++qq) {
    bf16x8 bfr = *(const bf16x8*)(wfc + ((size_t)((ks * 14 + qq) * 32 + n16)) * 512 + lane * 8);
#pragma unroll
    for (int m4 = 0; m4 < 4; ++m4) {
      bf16x8 a = *(const bf16x8*)(A6 + (size_t)(rbase + m4 * 16) * 3136 + kb + qq * 32);
      acc[m4] = __builtin_amdgcn_mfma_f32_16x16x32_bf16(a, bfr, acc[m4], 0, 0, 0);
    }
  }
#pragma unroll
  for (int m4 = 0; m4 < 4; ++m4)
#pragma unroll
    for (int j = 0; j < 4; ++j) {
      int row = mt * 64 + m4 * 16 + (lane >> 4) * 4 + j;
      int col = nt * 64 + w * 16 + (lane & 15);
      part[((size_t)ks * 256 + row) * 512 + col] = acc[m4][j];
    }
}

// ---- FC2 fused with k-split reduce + bias + ELU + log_softmax --------------
__global__ __launch_bounds__(64) void fc2_kernel(
    const float* __restrict__ part, const float* __restrict__ fc1b,
    const float* __restrict__ W, const float* __restrict__ bias,
    float* __restrict__ out) {
  int bb = blockIdx.x;
  int t = threadIdx.x;
  float acc[10];
#pragma unroll
  for (int o = 0; o < 10; ++o) acc[o] = 0.f;
  for (int k = t; k < 512; k += 64) {
    float s = fc1b[k];
#pragma unroll
    for (int ks = 0; ks < 7; ++ks) s += part[(size_t)ks * 131072 + bb * 512 + k];
    float xv = eluf(s);
#pragma unroll
    for (int o = 0; o < 10; ++o) acc[o] = fmaf(xv, W[k * 10 + o], acc[o]);
  }
#pragma unroll
  for (int o = 0; o < 10; ++o) {
    float v = acc[o];
#pragma unroll
    for (int s = 32; s >= 1; s >>= 1) v += __shfl_xor(v, s);
    acc[o] = v + bias[o];
  }
  float m = acc[0];
#pragma unroll
  for (int o = 1; o < 10; ++o) m = fmaxf(m, acc[o]);
  float sum = 0.f;
#pragma unroll
  for (int o = 0; o < 10; ++o) sum += __expf(acc[o] - m);
  float lse = m + __logf(sum);
  if (t < 10) out[bb * 10 + t] = acc[t] - lse;
}

extern "C" void kernel_launch(void* const* d_in, const int* in_sizes, int n_in,
                              void* d_out, int out_size, void* d_ws, size_t ws_size,
                              hipStream_t stream) {
  const float* x    = (const float*)d_in[0];
  const float* W1   = (const float*)d_in[7];
  const float* r1   = (const float*)d_in[8];
  const float* b1   = (const float*)d_in[9];
  const float* W2   = (const float*)d_in[10];
  const float* r2   = (const float*)d_in[11];
  const float* b2   = (const float*)d_in[12];
  const float* W3   = (const float*)d_in[13];
  const float* r3   = (const float*)d_in[14];
  const float* b3   = (const float*)d_in[15];
  const float* W4   = (const float*)d_in[16];
  const float* r4   = (const float*)d_in[17];
  const float* b4   = (const float*)d_in[18];
  const float* fc1W = (const float*)d_in[19];
  const float* fc1b = (const float*)d_in[20];
  const float* fc2W = (const float*)d_in[21];
  const float* fc2b = (const float*)d_in[22];

  char* wsb = (char*)d_ws;
  float* wf1  = (float*)(wsb + 0);        // 1024 B
  u16*   wp2  = (u16*)(wsb + 1024);       // 18432 B
  u16*   wp3  = (u16*)(wsb + 19456);      // 36864 B
  u16*   wp4  = (u16*)(wsb + 56320);      // 73728 B
  u16*   wfc  = (u16*)(wsb + 130048);     // 3211264 B
  u16*   A6   = (u16*)(wsb + 3341312);    // 1605632 B  [256][3136] bf16
  float* part = (float*)(wsb + 4946944);  // 3670016 B  [7][256][512] f32

  pack_all<<<6525, 256, 0, stream>>>(W1, W2, r2, W3, r3, W4, r4, fc1W,
                                     wf1, wp2, wp3, wp4, wfc);

  (void)hipFuncSetAttribute((const void*)conv_mega,
                            hipFuncAttributeMaxDynamicSharedMemorySize, 111744);
  conv_mega<<<256, 512, 111744, stream>>>(x, wf1, r1, b1, wp2, b2, wp3, b3,
                                          wp4, b4, A6);

  fc1_mfma<<<224, 256, 0, stream>>>(A6, wfc, part);
  fc2_kernel<<<256, 64, 0, stream>>>(part, fc1b, fc2W, fc2b, (float*)d_out);
}

// Round 4
// 54.412 us; speedup vs baseline: 5.1824x; 1.1420x over previous
//
#include <hip/hip_runtime.h>

typedef unsigned short u16;
typedef short bf16x8 __attribute__((ext_vector_type(8)));   // 8 bf16 in 4 VGPRs
typedef float f32x4 __attribute__((ext_vector_type(4)));

__device__ __constant__ const int DRS[8] = {-1,-1,-1, 0, 0, 1, 1, 1};
__device__ __constant__ const int DCS[8] = {-1, 0, 1,-1, 1,-1, 0, 1};

__device__ inline float bf2f(u16 u) { return __uint_as_float(((unsigned)u) << 16); }
__device__ inline u16 f2bf(float f) {            // round-to-nearest-even
  unsigned u = __float_as_uint(f);
  return (u16)((u + 0x7fffu + ((u >> 16) & 1u)) >> 16);
}
__device__ inline float eluf(float v) { return v > 0.f ? v : (__expf(v) - 1.f); }

// collapse degree-1 B-spline weights for grid direction d (0..7, center skipped)
__device__ inline float weff_val(const float* __restrict__ W, int d, int off, int stride) {
  int dd = d >= 4 ? d + 1 : d;
  int dr = dd / 3 - 1, dc = dd - (dd / 3) * 3 - 1;
  int kr0, kr1, nr; float wr0, wr1;
  if (dr < 0)       { kr0 = 0; wr0 = 1.f; kr1 = 0; wr1 = 0.f; nr = 1; }
  else if (dr == 0) { kr0 = 1; wr0 = .5f; kr1 = 2; wr1 = .5f; nr = 2; }
  else              { kr0 = 3; wr0 = 1.f; kr1 = 0; wr1 = 0.f; nr = 1; }
  int kc0, kc1, nc; float wc0, wc1;
  if (dc < 0)       { kc0 = 0; wc0 = 1.f; kc1 = 0; wc1 = 0.f; nc = 1; }
  else if (dc == 0) { kc0 = 1; wc0 = .5f; kc1 = 2; wc1 = .5f; nc = 2; }
  else              { kc0 = 3; wc0 = 1.f; kc1 = 0; wc1 = 0.f; nc = 1; }
  float acc = wr0 * wc0 * W[(kr0 * 4 + kc0) * stride + off];
  if (nc == 2) acc += wr0 * wc1 * W[(kr0 * 4 + kc1) * stride + off];
  if (nr == 2) {
    acc += wr1 * wc0 * W[(kr1 * 4 + kc0) * stride + off];
    if (nc == 2) acc += wr1 * wc1 * W[(kr1 * 4 + kc1) * stride + off];
  }
  return acc;
}

// ---- pack kernel: blocks 0..97 = fc1W LDS-transpose; blocks 98.. = small packs
__global__ __launch_bounds__(256) void pack_all(
    const float* __restrict__ W1,
    const float* __restrict__ W2, const float* __restrict__ rt2,
    const float* __restrict__ W3, const float* __restrict__ rt3,
    const float* __restrict__ W4, const float* __restrict__ rt4,
    const float* __restrict__ fcW,
    float* __restrict__ wf1, u16* __restrict__ wp2,
    u16* __restrict__ wp3, u16* __restrict__ wp4, u16* __restrict__ wfc) {
  __shared__ u16 T[32 * 514];
  int blk = blockIdx.x, t = threadIdx.x;
  if (blk < 98) {              // fc1W transpose-pack: q-slab = rows 32q..32q+31
    int q = blk;
#pragma unroll
    for (int i = 0; i < 16; ++i) {               // coalesced float4 reads
      int idx = i * 1024 + t * 4;
      int k = idx >> 9, n = idx & 511;
      float4 v = *reinterpret_cast<const float4*>(fcW + (size_t)(q * 32 + k) * 512 + n);
      T[k * 514 + n]     = f2bf(v.x);
      T[k * 514 + n + 1] = f2bf(v.y);
      T[k * 514 + n + 2] = f2bf(v.z);
      T[k * 514 + n + 3] = f2bf(v.w);
    }
    __syncthreads();
#pragma unroll
    for (int w = 0; w < 8; ++w) {                // coalesced 16B fragment writes
      int g = w * 256 + t;
      int nt = g >> 6, l = g & 63;
      union { int4 q4; u16 s[8]; } R;
#pragma unroll
      for (int j = 0; j < 8; ++j)
        R.s[j] = T[((l >> 4) * 8 + j) * 514 + nt * 16 + (l & 15)];
      *reinterpret_cast<int4*>(wfc + ((size_t)(q * 32 + nt) * 64 + l) * 8) = R.q4;
    }
    return;
  }
  int idx = (blk - 98) * 256 + t;                // small packs (< 64768)
  if (idx < 256) {                               // weff1 fp32 [8][32]
    int d = idx >> 5, o = idx & 31;
    wf1[idx] = weff_val(W1, d, o, 32);
    return;
  }
  if (idx < 9472) {                              // wp2: CT=2 KQ=1
    int local = idx - 256;
    int j = local & 7, l = (local >> 3) & 63, chunk = local >> 9;
    int ct = chunk & 1, tap = chunk >> 1;
    int k = (l >> 4) * 8 + j, n = ct * 16 + (l & 15);
    float v = tap < 8 ? weff_val(W2, tap, k * 32 + n, 1024) : rt2[k * 32 + n];
    wp2[local] = f2bf(v);
    return;
  }
  if (idx < 27904) {                             // wp3: CT=4 KQ=1
    int local = idx - 9472;
    int j = local & 7, l = (local >> 3) & 63, chunk = local >> 9;
    int ct = chunk & 3, tap = chunk >> 2;
    int k = (l >> 4) * 8 + j, n = ct * 16 + (l & 15);
    float v = tap < 8 ? weff_val(W3, tap, k * 64 + n, 2048) : rt3[k * 64 + n];
    wp3[local] = f2bf(v);
    return;
  }
  if (idx < 64768) {                             // wp4: CT=4 KQ=2
    int local = idx - 27904;
    int j = local & 7, l = (local >> 3) & 63, chunk = local >> 9;
    int q = chunk & 1, tmp = chunk >> 1;
    int ct = tmp & 3, tap = tmp >> 2;
    int k = q * 32 + (l >> 4) * 8 + j, n = ct * 16 + (l & 15);
    float v = tap < 8 ? weff_val(W4, tap, k * 64 + n, 4096) : rt4[k * 64 + n];
    wp4[local] = f2bf(v);
  }
}

// ---- mega conv kernel: block = 1 image (1024 thr, 16 waves), LDS-resident ---
// LDS (bytes), temporally overlapped:
//   early : H1 [0,61568) 4 grp stride 962 int4 | XT [61568,65408) f32 30x32
//   mid   : H2 [75520,125696) [784][32] u16
//   late  : H3 [0,16512) 4 grp stride 258 int4 | H4 [42496,75520) 8 grp stride 258
//           H5 [17408,42496) [196][64] u16
// total dynamic = 125696 B  (1 block/CU)
__global__ __launch_bounds__(1024) void conv_mega(
    const float* __restrict__ x,
    const float* __restrict__ wf1, const float* __restrict__ rt1, const float* __restrict__ b1,
    const u16* __restrict__ wp2, const float* __restrict__ b2,
    const u16* __restrict__ wp3, const float* __restrict__ b3,
    const u16* __restrict__ wp4, const float* __restrict__ b4,
    u16* __restrict__ A6) {
  extern __shared__ char smem[];
  int4* H1 = (int4*)smem;
  int4* H3 = (int4*)smem;
  u16*  H5 = (u16*)(smem + 17408);
  int4* H4 = (int4*)(smem + 42496);
  u16*  H4u = (u16*)(smem + 42496);
  float* XT = (float*)(smem + 61568);
  int4* H2 = (int4*)(smem + 75520);
  u16*  H2u = (u16*)(smem + 75520);

  int img = blockIdx.x, tid = threadIdx.x;
  int lane = tid & 63, wid = tid >> 6;
  int kcb = lane >> 4, n0 = lane & 15;
  int4 z4 = make_int4(0, 0, 0, 0);

  // phase A: zero H1 (incl pads) + build padded XT
  for (int i = tid; i < 3848; i += 1024) H1[i] = z4;
  if (tid < 960) {
    int r = tid >> 5, c = tid & 31;
    bool in = (r >= 1) && (r <= 28) && (c >= 1) && (c <= 28);
    XT[tid] = in ? x[(size_t)img * 784 + (r - 1) * 28 + (c - 1)] : 0.f;
  }
  __syncthreads();

  // ---- conv1 (Cin=1, fp32) -> H1 bf16 chunks ----
  if (tid < 784) {
    int px = tid;
    int r = px / 28, c = px - 28 * (px / 28);
    float acc[32];
#pragma unroll
    for (int o = 0; o < 32; ++o) acc[o] = 0.f;
#pragma unroll
    for (int d = 0; d < 8; ++d) {
      float xv = XT[(r + 1 - DRS[d]) * 32 + (c + 1 - DCS[d])];
#pragma unroll
      for (int o = 0; o < 32; ++o) acc[o] = fmaf(xv, wf1[d * 32 + o], acc[o]);
    }
    float inv = 1.f / (float)((3 - (r == 0) - (r == 27)) * (3 - (c == 0) - (c == 27)) - 1);
    float xc = XT[(r + 1) * 32 + c + 1];
    unsigned pk[16];
#pragma unroll
    for (int h = 0; h < 16; ++h) {
      float v0 = eluf(acc[2 * h] * inv + xc * rt1[2 * h] + b1[2 * h]);
      float v1 = eluf(acc[2 * h + 1] * inv + xc * rt1[2 * h + 1] + b1[2 * h + 1]);
      pk[h] = (unsigned)f2bf(v0) | ((unsigned)f2bf(v1) << 16);
    }
#pragma unroll
    for (int kc = 0; kc < 4; ++kc)
      H1[kc * 962 + (r + 1) * 32 + (c + 1)] =
          make_int4(pk[4 * kc], pk[4 * kc + 1], pk[4 * kc + 2], pk[4 * kc + 3]);
  }
  __syncthreads();

  // ---- conv2 (32->32, MFMA): 16 waves = 2 cout-halves x 8 tile-strides ----
  {
    int ctg = wid & 1, t0 = wid >> 1;
    bf16x8 w2[9];
#pragma unroll
    for (int tap = 0; tap < 9; ++tap)
      w2[tap] = *(const bf16x8*)(wp2 + (tap * 2 + ctg) * 512 + lane * 8);
    for (int t = t0; t < 49; t += 8) {
      int pxm = t * 16 + n0;
      int r = pxm / 28, c = pxm - 28 * (pxm / 28);
      f32x4 an = {0,0,0,0}, ar = {0,0,0,0};
#pragma unroll
      for (int d = 0; d < 8; ++d) {
        bf16x8 a = *(const bf16x8*)&H1[kcb * 962 + (r + 1 - DRS[d]) * 32 + (c + 1 - DCS[d])];
        an = __builtin_amdgcn_mfma_f32_16x16x32_bf16(a, w2[d], an, 0, 0, 0);
      }
      {
        bf16x8 a = *(const bf16x8*)&H1[kcb * 962 + (r + 1) * 32 + (c + 1)];
        ar = __builtin_amdgcn_mfma_f32_16x16x32_bf16(a, w2[8], ar, 0, 0, 0);
      }
#pragma unroll
      for (int j = 0; j < 4; ++j) {
        int pm = t * 16 + (lane >> 4) * 4 + j;
        int rm = pm / 28, cm = pm - 28 * (pm / 28);
        float inv = 1.f / (float)((3 - (rm == 0) - (rm == 27)) * (3 - (cm == 0) - (cm == 27)) - 1);
        H2u[pm * 32 + ctg * 16 + n0] = f2bf(eluf(an[j] * inv + ar[j] + b2[ctg * 16 + n0]));
      }
    }
  }
  __syncthreads();

  // ---- pool0: H2 -> H3 padded; zero H4 pads concurrently ----
  for (int i = tid; i < 1032; i += 1024) {
    int kc = i / 258, rem = i - 258 * kc;
    int4 v = z4;
    if (rem < 256) {
      int pr = rem >> 4, pc = rem & 15;
      if (pr >= 1 && pr <= 14 && pc >= 1 && pc <= 14) {
        int px0 = (2 * (pr - 1)) * 28 + 2 * (pc - 1);
        union { int4 q; u16 s[8]; } A, B, C, D, R;
        A.q = H2[px0 * 4 + kc]; B.q = H2[(px0 + 1) * 4 + kc];
        C.q = H2[(px0 + 28) * 4 + kc]; D.q = H2[(px0 + 29) * 4 + kc];
#pragma unroll
        for (int e = 0; e < 8; ++e)
          R.s[e] = f2bf(fmaxf(fmaxf(bf2f(A.s[e]), bf2f(B.s[e])),
                              fmaxf(bf2f(C.s[e]), bf2f(D.s[e]))));
        v = R.q;
      }
    }
    H3[i] = v;
  }
  for (int i = tid; i < 2064; i += 1024) H4[i] = z4;
  __syncthreads();

  // ---- conv3 (32->64, MFMA): 16 waves = 4 cout-tiles x 4 tile-strides ----
  int ctg = wid & 3, t0 = wid >> 2;
  {
    bf16x8 w3[9];
#pragma unroll
    for (int tap = 0; tap < 9; ++tap)
      w3[tap] = *(const bf16x8*)(wp3 + (tap * 4 + ctg) * 512 + lane * 8);
    for (int t = t0; t < 13; t += 4) {
      int pxm = t * 16 + n0; if (pxm > 195) pxm = 195;
      int r = pxm / 14, c = pxm - 14 * (pxm / 14);
      f32x4 an = {0,0,0,0}, ar = {0,0,0,0};
#pragma unroll
      for (int d = 0; d < 8; ++d) {
        bf16x8 a = *(const bf16x8*)&H3[kcb * 258 + (r + 1 - DRS[d]) * 16 + (c + 1 - DCS[d])];
        an = __builtin_amdgcn_mfma_f32_16x16x32_bf16(a, w3[d], an, 0, 0, 0);
      }
      {
        bf16x8 a = *(const bf16x8*)&H3[kcb * 258 + (r + 1) * 16 + (c + 1)];
        ar = __builtin_amdgcn_mfma_f32_16x16x32_bf16(a, w3[8], ar, 0, 0, 0);
      }
#pragma unroll
      for (int j = 0; j < 4; ++j) {
        int pm = t * 16 + (lane >> 4) * 4 + j;
        if (pm < 196) {
          int rm = pm / 14, cm = pm - 14 * (pm / 14);
          float inv = 1.f / (float)((3 - (rm == 0) - (rm == 13)) * (3 - (cm == 0) - (cm == 13)) - 1);
          int n = ctg * 16 + n0;
          float v = eluf(an[j] * inv + ar[j] + b3[n]);
          H4u[((n >> 3) * 258 + (rm + 1) * 16 + (cm + 1)) * 8 + (n & 7)] = f2bf(v);
        }
      }
    }
  }
  __syncthreads();

  // ---- conv4 (64->64, MFMA, KQ=2) H4 -> H5 ----
  {
    bf16x8 w4[9][2];
#pragma unroll
    for (int tap = 0; tap < 9; ++tap)
#pragma unroll
      for (int q = 0; q < 2; ++q)
        w4[tap][q] = *(const bf16x8*)(wp4 + ((tap * 4 + ctg) * 2 + q) * 512 + lane * 8);
    for (int t = t0; t < 13; t += 4) {
      int pxm = t * 16 + n0; if (pxm > 195) pxm = 195;
      int r = pxm / 14, c = pxm - 14 * (pxm / 14);
      f32x4 an = {0,0,0,0}, ar = {0,0,0,0};
#pragma unroll
      for (int d = 0; d < 8; ++d) {
        int rr = r + 1 - DRS[d], c2 = c + 1 - DCS[d];
#pragma unroll
        for (int q = 0; q < 2; ++q) {
          bf16x8 a = *(const bf16x8*)&H4[(q * 4 + kcb) * 258 + rr * 16 + c2];
          an = __builtin_amdgcn_mfma_f32_16x16x32_bf16(a, w4[d][q], an, 0, 0, 0);
        }
      }
#pragma unroll
      for (int q = 0; q < 2; ++q) {
        bf16x8 a = *(const bf16x8*)&H4[(q * 4 + kcb) * 258 + (r + 1) * 16 + (c + 1)];
        ar = __builtin_amdgcn_mfma_f32_16x16x32_bf16(a, w4[8][q], ar, 0, 0, 0);
      }
#pragma unroll
      for (int j = 0; j < 4; ++j) {
        int pm = t * 16 + (lane >> 4) * 4 + j;
        if (pm < 196) {
          int rm = pm / 14, cm = pm - 14 * (pm / 14);
          float inv = 1.f / (float)((3 - (rm == 0) - (rm == 13)) * (3 - (cm == 0) - (cm == 13)) - 1);
          int n = ctg * 16 + n0;
          H5[pm * 64 + n] = f2bf(eluf(an[j] * inv + ar[j] + b4[n]));
        }
      }
    }
  }
  __syncthreads();

  // ---- pool1: H5 [196][64] -> global A6 [img][49*64] bf16 ----
  if (tid < 392) {
    int kc = tid & 7, q = tid >> 3;
    int r2 = q / 7, c2 = q - 7 * (q / 7);
    int px0 = (2 * r2) * 14 + 2 * c2;
    union { int4 q4; u16 s[8]; } A, B, C, D, R;
    A.q4 = *(const int4*)&H5[px0 * 64 + kc * 8];
    B.q4 = *(const int4*)&H5[(px0 + 1) * 64 + kc * 8];
    C.q4 = *(const int4*)&H5[(px0 + 14) * 64 + kc * 8];
    D.q4 = *(const int4*)&H5[(px0 + 15) * 64 + kc * 8];
#pragma unroll
    for (int e = 0; e < 8; ++e)
      R.s[e] = f2bf(fmaxf(fmaxf(bf2f(A.s[e]), bf2f(B.s[e])),
                          fmaxf(bf2f(C.s[e]), bf2f(D.s[e]))));
    *(int4*)(A6 + ((size_t)img * 49 + q) * 64 + kc * 8) = R.q4;
  }
}

// ---- FC1 bf16 MFMA: [256,3136]x[3136,512], k-split 14, 64x64 tiles ---------
__global__ __launch_bounds__(256) void fc1_mfma(
    const u16* __restrict__ A6, const u16* __restrict__ wfc,
    float* __restrict__ part) {
  int blk = blockIdx.x;              // 448 = 14 ks x (4 mt x 8 nt4)
  int ks = blk >> 5;
  int rem = blk & 31;
  int mt = rem & 3, nt4 = rem >> 2;
  int lane = threadIdx.x & 63, w = threadIdx.x >> 6;
  int NT = nt4 * 4 + w;
  f32x4 acc[4];
#pragma unroll
  for (int m4 = 0; m4 < 4; ++m4) acc[m4] = {0.f, 0.f, 0.f, 0.f};
  int rbase = mt * 64 + (lane & 15);
  int kb = ks * 224 + (lane >> 4) * 8;
#pragma unroll
  for (int qq = 0; qq < 7; ++qq) {
    bf16x8 bfr = *(const bf16x8*)(wfc + ((size_t)((ks * 7 + qq) * 32 + NT) * 64 + lane) * 8);
#pragma unroll
    for (int m4 = 0; m4 < 4; ++m4) {
      bf16x8 a = *(const bf16x8*)(A6 + (size_t)(rbase + m4 * 16) * 3136 + kb + qq * 32);
      acc[m4] = __builtin_amdgcn_mfma_f32_16x16x32_bf16(a, bfr, acc[m4], 0, 0, 0);
    }
  }
#pragma unroll
  for (int m4 = 0; m4 < 4; ++m4)
#pragma unroll
    for (int j = 0; j < 4; ++j) {
      int row = mt * 64 + m4 * 16 + (lane >> 4) * 4 + j;
      int col = NT * 16 + (lane & 15);
      part[((size_t)ks * 256 + row) * 512 + col] = acc[m4][j];
    }
}

// ---- FC2 fused with k-split reduce + bias + ELU + log_softmax --------------
__global__ __launch_bounds__(64) void fc2_kernel(
    const float* __restrict__ part, const float* __restrict__ fc1b,
    const float* __restrict__ W, const float* __restrict__ bias,
    float* __restrict__ out) {
  int bb = blockIdx.x;
  int t = threadIdx.x;
  float acc[10];
#pragma unroll
  for (int o = 0; o < 10; ++o) acc[o] = 0.f;
  for (int k = t; k < 512; k += 64) {
    float s = fc1b[k];
#pragma unroll
    for (int ks = 0; ks < 14; ++ks) s += part[(size_t)ks * 131072 + bb * 512 + k];
    float xv = eluf(s);
#pragma unroll
    for (int o = 0; o < 10; ++o) acc[o] = fmaf(xv, W[k * 10 + o], acc[o]);
  }
#pragma unroll
  for (int o = 0; o < 10; ++o) {
    float v = acc[o];
#pragma unroll
    for (int s = 32; s >= 1; s >>= 1) v += __shfl_xor(v, s);
    acc[o] = v + bias[o];
  }
  float m = acc[0];
#pragma unroll
  for (int o = 1; o < 10; ++o) m = fmaxf(m, acc[o]);
  float sum = 0.f;
#pragma unroll
  for (int o = 0; o < 10; ++o) sum += __expf(acc[o] - m);
  float lse = m + __logf(sum);
  if (t < 10) out[bb * 10 + t] = acc[t] - lse;
}

extern "C" void kernel_launch(void* const* d_in, const int* in_sizes, int n_in,
                              void* d_out, int out_size, void* d_ws, size_t ws_size,
                              hipStream_t stream) {
  const float* x    = (const float*)d_in[0];
  const float* W1   = (const float*)d_in[7];
  const float* r1   = (const float*)d_in[8];
  const float* b1   = (const float*)d_in[9];
  const float* W2   = (const float*)d_in[10];
  const float* r2   = (const float*)d_in[11];
  const float* b2   = (const float*)d_in[12];
  const float* W3   = (const float*)d_in[13];
  const float* r3   = (const float*)d_in[14];
  const float* b3   = (const float*)d_in[15];
  const float* W4   = (const float*)d_in[16];
  const float* r4   = (const float*)d_in[17];
  const float* b4   = (const float*)d_in[18];
  const float* fc1W = (const float*)d_in[19];
  const float* fc1b = (const float*)d_in[20];
  const float* fc2W = (const float*)d_in[21];
  const float* fc2b = (const float*)d_in[22];

  char* wsb = (char*)d_ws;
  float* wf1  = (float*)(wsb + 0);        // 1024 B
  u16*   wp2  = (u16*)(wsb + 1024);       // 18432 B
  u16*   wp3  = (u16*)(wsb + 19456);      // 36864 B
  u16*   wp4  = (u16*)(wsb + 56320);      // 73728 B
  u16*   wfc  = (u16*)(wsb + 130048);     // 3211264 B
  u16*   A6   = (u16*)(wsb + 3341312);    // 1605632 B  [256][3136] bf16
  float* part = (float*)(wsb + 4946944);  // 7340032 B  [14][256][512] f32

  pack_all<<<351, 256, 0, stream>>>(W1, W2, r2, W3, r3, W4, r4, fc1W,
                                    wf1, wp2, wp3, wp4, wfc);

  (void)hipFuncSetAttribute((const void*)conv_mega,
                            hipFuncAttributeMaxDynamicSharedMemorySize, 125696);
  conv_mega<<<256, 1024, 125696, stream>>>(x, wf1, r1, b1, wp2, b2, wp3, b3,
                                           wp4, b4, A6);

  fc1_mfma<<<448, 256, 0, stream>>>(A6, wfc, part);
  fc2_kernel<<<256, 64, 0, stream>>>(part, fc1b, fc2W, fc2b, (float*)d_out);
}